// Round 5
// baseline (76.897 us; speedup 1.0000x reference)
//
#include <hip/hip_runtime.h>

#define NN 2048
#define NT 256          // threads per block (4 waves)
#define NB 4
#define NC 16
#define NCLS (NB * NC)
#define CHUNKS 8        // rank blocks per class
#define TILE 64
#define NTILES (NN / TILE)
#define KKEEP 176       // >= (K-1) + 64 = 163

typedef unsigned long long u64;

// key = (~orderable(score) << 32) | idx  -> ascending u64 == (score desc, idx asc)
__device__ __forceinline__ u64 make_key(float s, int idx) {
  unsigned u = __float_as_uint(s);
  u ^= (u >> 31) ? 0xFFFFFFFFu : 0x80000000u;  // ascending-orderable
  u = ~u;                                      // descending score
  return ((u64)u << 32) | (unsigned)idx;
}
__device__ __forceinline__ float key_score(u64 key) {
  unsigned u = ~(unsigned)(key >> 32);
  unsigned bits = (u >> 31) ? (u ^ 0x80000000u) : ~u;
  return __uint_as_float(bits);
}

// IoU with the exact op order of the reference; asm guard blocks
// ffp-contract from fusing (ka + a - iw*ih) into an FMA.
__device__ __forceinline__ float iou_f(float kx1, float ky1, float kx2, float ky2, float ka,
                                       float x1, float y1, float x2, float y2, float a) {
  float ix1 = fmaxf(kx1, x1);
  float iy1 = fmaxf(ky1, y1);
  float ix2 = fminf(kx2, x2);
  float iy2 = fminf(ky2, y2);
  float iw = fmaxf(ix2 - ix1, 0.0f);
  float ih = fmaxf(iy2 - iy1, 0.0f);
  float inter = iw * ih;
  asm volatile("" : "+v"(inter));
  float denom = ka + a - inter;
  return inter / denom;
}

// ---------------- kernel 0: build sort keys in global memory ----------------
__global__ __launch_bounds__(NT) void key_kernel(
    const float* __restrict__ scores, u64* __restrict__ keys)
{
  const int bc = blockIdx.x;
  const int t  = threadIdx.x;
  const float4* s4 = (const float4*)(scores + (size_t)bc * NN);
  float4 v0 = s4[t * 2], v1 = s4[t * 2 + 1];
  const int g = t * 8;
  u64* kp = keys + (size_t)bc * NN + g;
  kp[0] = make_key(v0.x, g + 0);
  kp[1] = make_key(v0.y, g + 1);
  kp[2] = make_key(v0.z, g + 2);
  kp[3] = make_key(v0.w, g + 3);
  kp[4] = make_key(v1.x, g + 4);
  kp[5] = make_key(v1.y, g + 5);
  kp[6] = make_key(v1.z, g + 6);
  kp[7] = make_key(v1.w, g + 7);
}

// ---------------- kernel 1: rank sort via scalar-broadcast scan ----------------
// 512 blocks = 64 classes x 8 chunks. The j-loop address is wave-uniform
// (kernel arg + loop counter) -> hipcc emits s_load (scalar pipe broadcast),
// so the per-key cost is one v_cmp_lt_u64 + carry-add on the VALU. No LDS.
__global__ __launch_bounds__(NT) void rank_kernel(
    const u64* __restrict__ keys,
    const float* __restrict__ boxes,
    float* __restrict__ wx1, float* __restrict__ wy1,
    float* __restrict__ wx2, float* __restrict__ wy2,
    float* __restrict__ wsc, int* __restrict__ widx)
{
  const int blk   = blockIdx.x;
  const int bc    = blk >> 3;       // class id 0..63
  const int chunk = blk & 7;
  const int b     = bc >> 4;        // batch
  const int t     = threadIdx.x;

  const u64* __restrict__ kcls = keys + (size_t)bc * NN;
  const int i = chunk * NT + t;
  const u64 my = kcls[i];

  // rank = # keys strictly less than mine (keys unique via idx).
  // 8 independent accumulators: backend batches the 8 consecutive uniform
  // loads into wide s_load and renames cmp destinations for ILP.
  int r0 = 0, r1 = 0, r2 = 0, r3 = 0, r4 = 0, r5 = 0, r6 = 0, r7 = 0;
  for (int j = 0; j < NN; j += 8) {
    r0 += (kcls[j + 0] < my) ? 1 : 0;
    r1 += (kcls[j + 1] < my) ? 1 : 0;
    r2 += (kcls[j + 2] < my) ? 1 : 0;
    r3 += (kcls[j + 3] < my) ? 1 : 0;
    r4 += (kcls[j + 4] < my) ? 1 : 0;
    r5 += (kcls[j + 5] < my) ? 1 : 0;
    r6 += (kcls[j + 6] < my) ? 1 : 0;
    r7 += (kcls[j + 7] < my) ? 1 : 0;
  }
  const int rank = ((r0 + r1) + (r2 + r3)) + ((r4 + r5) + (r6 + r7));

  // gather my box, fix min/max, scatter to sorted position
  const int idx = (int)(unsigned)(my & 0xFFFFFFFFu);
  float4 v = *(const float4*)(boxes + ((size_t)b * NN + idx) * 4);
  float x1 = fminf(v.x, v.z), x2 = fmaxf(v.x, v.z);
  float y1 = fminf(v.y, v.w), y2 = fmaxf(v.y, v.w);

  const size_t o = (size_t)bc * NN + rank;
  wx1[o] = x1; wy1[o] = y1;
  wx2[o] = x2; wy2[o] = y2;
  wsc[o] = key_score(my);
  widx[o] = idx;
}

// ---------------- kernel 2: per-class tiled greedy NMS ----------------
__global__ __launch_bounds__(NT) void greedy_kernel(
    const float* __restrict__ wx1, const float* __restrict__ wy1,
    const float* __restrict__ wx2, const float* __restrict__ wy2,
    const float* __restrict__ wsc, const int* __restrict__ widx,
    const float* __restrict__ iou_thr_p, const float* __restrict__ score_thr_p,
    int K, int* __restrict__ out)
{
  __shared__ float s_kx1[KKEEP], s_ky1[KKEEP], s_kx2[KKEEP], s_ky2[KKEEP], s_ka[KKEEP];
  __shared__ float s_tx1[TILE], s_ty1[TILE], s_tx2[TILE], s_ty2[TILE], s_ts[TILE];
  __shared__ int   s_tidx[TILE];
  __shared__ u64   s_colmask[4][TILE];
  __shared__ u64   s_dead[4];
  __shared__ int   s_total;

  const int bc = blockIdx.x;
  const int b  = bc >> 4;
  const int c  = bc & 15;
  const int t  = threadIdx.x;
  const int wv = t >> 6;
  const int ln = t & 63;

  const float iou_thr = *iou_thr_p;
  const float sthr    = *score_thr_p;

  int* orow = out + (size_t)bc * K * 3;
  for (int i = t; i < K * 3; i += NT) orow[i] = -1;
  if (t == 0) s_total = 0;

  const size_t base0 = (size_t)bc * NN;
  __syncthreads();

  for (int tile = 0; tile < NTILES; tile++) {
    const int base = tile * TILE;

    // load tile data into LDS (each wave loads distinct arrays)
    if      (wv == 0) { s_tx1[ln] = wx1[base0 + base + ln]; s_ts[ln]   = wsc[base0 + base + ln]; }
    else if (wv == 1) { s_ty1[ln] = wy1[base0 + base + ln]; s_tidx[ln] = widx[base0 + base + ln]; }
    else if (wv == 2) { s_tx2[ln] = wx2[base0 + base + ln]; }
    else              { s_ty2[ln] = wy2[base0 + base + ln]; }
    const int kcount = s_total;       // stable: last written before previous barrier
    __syncthreads();

    // Phase B: column ln owned per-wave; intra-tile triangle rows wv*16..+15
    // plus suppression vs kept list (strided by wave).
    float jx1 = s_tx1[ln], jy1 = s_ty1[ln], jx2 = s_tx2[ln], jy2 = s_ty2[ln];
    float ja  = (jx2 - jx1) * (jy2 - jy1);   // bit-identical to reference area
    u64 m = 0ULL;
    for (int r = 0; r < 16; r++) {
      int il = wv * 16 + r;
      if (il < ln) {
        float rx1 = s_tx1[il], ry1 = s_ty1[il], rx2 = s_tx2[il], ry2 = s_ty2[il];
        float ra  = (rx2 - rx1) * (ry2 - ry1);
        float iou = iou_f(rx1, ry1, rx2, ry2, ra, jx1, jy1, jx2, jy2, ja);
        if (iou > iou_thr) m |= (1ULL << il);
      }
    }
    s_colmask[wv][ln] = m;

    bool dead = false;
    for (int ki = wv; ki < kcount; ki += 4) {
      float iou = iou_f(s_kx1[ki], s_ky1[ki], s_kx2[ki], s_ky2[ki], s_ka[ki],
                        jx1, jy1, jx2, jy2, ja);
      if (iou > iou_thr) { dead = true; break; }
    }
    s_dead[wv] = __ballot(dead);
    __syncthreads();

    // Phase C: wave 0 resolves intra-tile greedy, appends kept, writes output
    if (t < 64) {
      u64 mc = s_colmask[0][ln] | s_colmask[1][ln] | s_colmask[2][ln] | s_colmask[3][ln];
      u64 alive = ~(s_dead[0] | s_dead[1] | s_dead[2] | s_dead[3]);
      for (int i = 0; i < TILE; i++) {
        if ((alive >> i) & 1ULL) {
          u64 kill = __ballot((int)((mc >> i) & 1ULL));
          alive &= ~kill;
        }
      }
      int total0 = s_total;
      bool kept = (alive >> ln) & 1ULL;
      int pos = __popcll(alive & ((1ULL << ln) - 1ULL));
      if (kept) {
        int kpos = total0 + pos;                 // <= 99 + 63 < KKEEP
        s_kx1[kpos] = jx1; s_ky1[kpos] = jy1;
        s_kx2[kpos] = jx2; s_ky2[kpos] = jy2; s_ka[kpos] = ja;
        if (kpos < K && s_ts[ln] >= sthr) {
          orow[kpos * 3 + 0] = b;
          orow[kpos * 3 + 1] = c;
          orow[kpos * 3 + 2] = s_tidx[ln];
        }
      }
      if (ln == 0) s_total = total0 + (int)__popcll(alive);
    }
    __syncthreads();
    if (s_total >= K) break;   // uniform; stable until next Phase C
  }
}

extern "C" void kernel_launch(void* const* d_in, const int* in_sizes, int n_in,
                              void* d_out, int out_size, void* d_ws, size_t ws_size,
                              hipStream_t stream) {
  const float* boxes  = (const float*)d_in[0];
  const float* scores = (const float*)d_in[1];
  const float* iou_p  = (const float*)d_in[3];
  const float* sth_p  = (const float*)d_in[4];
  int* out = (int*)d_out;

  const int K = out_size / (NCLS * 3);
  const size_t plane = (size_t)NCLS * NN;

  float* w   = (float*)d_ws;
  float* wx1 = w + 0 * plane;
  float* wy1 = w + 1 * plane;
  float* wx2 = w + 2 * plane;
  float* wy2 = w + 3 * plane;
  float* wsc = w + 4 * plane;
  int*  widx = (int*)(w + 5 * plane);
  u64*  keys = (u64*)(w + 6 * plane);   // 8-byte aligned (plane is even)

  hipLaunchKernelGGL(key_kernel, dim3(NCLS), dim3(NT), 0, stream, scores, keys);
  hipLaunchKernelGGL(rank_kernel, dim3(NCLS * CHUNKS), dim3(NT), 0, stream,
                     keys, boxes, wx1, wy1, wx2, wy2, wsc, widx);
  hipLaunchKernelGGL(greedy_kernel, dim3(NCLS), dim3(NT), 0, stream,
                     wx1, wy1, wx2, wy2, wsc, widx, iou_p, sth_p, K, out);
}